// Round 9
// baseline (232.412 us; speedup 1.0000x reference)
//
#include <hip/hip_runtime.h>
#include <float.h>
#include <math.h>

// Problem constants: query (8,512,64,64) f32, keys (2000,512) f32
constexpr int D_  = 512;
constexpr int HW_ = 4096;           // 64*64
constexpr int N_  = 32768;          // B*HW
constexpr int M_  = 2000;
constexpr int MP_ = 2048;           // padded key count

typedef _Float16 half8 __attribute__((ext_vector_type(8)));
typedef float    f32x4 __attribute__((ext_vector_type(4)));

// ---------------- kernel 1: fused per-pixel rnorm + fp16 A-fragment swizzle ----------------
// qsw holds NORMALIZED q-hat (score downstream: s = kn - 2*acc; rnorm applied ONCE, here).
// qsw[pb][kb][lane][j]: lane L holds A[m = pb*16 + (L&15)][k = kb*32 + (L>>4)*8 + j]
__global__ __launch_bounds__(256) void k_prep(const float* __restrict__ q,
                                              float* __restrict__ rnorm,
                                              _Float16* __restrict__ qsw) {
    __shared__ float  tile[64][65];
    __shared__ float4 part2[16][17];
    __shared__ float  rns[64];
    int t = threadIdx.x;
    int p0 = blockIdx.x * 64;                    // 64 | 4096 -> single batch per block
    const float* base = q + (size_t)(p0 / HW_) * (D_ * HW_) + (p0 % HW_);

    // pass 1: sum of squares, float4-vectorized along hw (4 pixels per thread-lane)
    int px4 = t & 15, cgi = t >> 4;              // 16 pixel-quads x 16 c-groups of 32
    {
        const float* bb = base + px4 * 4;
        float s0 = 0.f, s1 = 0.f, s2 = 0.f, s3 = 0.f;
        for (int c = cgi * 32; c < cgi * 32 + 32; ++c) {
            float4 v = *(const float4*)(bb + (size_t)c * HW_);
            s0 += v.x * v.x; s1 += v.y * v.y; s2 += v.z * v.z; s3 += v.w * v.w;
        }
        part2[px4][cgi] = make_float4(s0, s1, s2, s3);
    }
    __syncthreads();
    if (t < 64) {
        float ss = 0.f;
#pragma unroll
        for (int g = 0; g < 16; ++g)
            ss += ((const float*)&part2[t >> 2][g])[t & 3];
        float rv = 1.0f / fmaxf(sqrtf(ss), 1e-12f);   // matches F.normalize eps
        rns[t] = rv;
        rnorm[p0 + t] = rv;
    }

    // pass 2: re-read (L2-hot), normalize, emit fragment-ordered fp16
    int pb0 = blockIdx.x * 4;
    for (int ct = 0; ct < 8; ++ct) {
        __syncthreads();                         // tile free + rns ready
#pragma unroll
        for (int i = 0; i < 4; ++i) {
            int sl = t + 256 * i;                // 1024 float4 slots: 64 ch-rows x 16
            int row = sl >> 4, p4 = (sl & 15) * 4;
            float4 v = *(const float4*)(base + (size_t)(ct * 64 + row) * HW_ + p4);
            tile[row][p4 + 0] = v.x; tile[row][p4 + 1] = v.y;
            tile[row][p4 + 2] = v.z; tile[row][p4 + 3] = v.w;
        }
        __syncthreads();
#pragma unroll
        for (int i = 0; i < 2; ++i) {
            int f = t + 256 * i;                 // 512 fragments: 8 tiles x 64 lanes
            int ti = f >> 6, L = f & 63;
            int pbi = ti & 3, kbi = ti >> 2;
            int plx = pbi * 16 + (L & 15);
            int cl = kbi * 32 + ((L >> 4) * 8);
            float rv = rns[plx];
            half8 hv;
#pragma unroll
            for (int j = 0; j < 8; ++j) hv[j] = (_Float16)(tile[cl + j][plx] * rv);
            size_t off = (((size_t)(pb0 + pbi) * 16 + (ct * 2 + kbi)) * 64 + L) * 8;
            *(half8*)(qsw + off) = hv;
        }
    }
}

// ---------------- kernel 2: |k|^2 (FLT_MAX for padding) ----------------
__global__ __launch_bounds__(256) void k_kn(const float* __restrict__ keys,
                                            float* __restrict__ kn) {
    int wave = threadIdx.x >> 6;
    int lane = threadIdx.x & 63;
    int m = blockIdx.x * 4 + wave;
    float s = 0.f;
    if (m < M_) {
        const float4* row = (const float4*)(keys + (size_t)m * D_);
        for (int j = lane; j < D_ / 4; j += 64) {
            float4 v = row[j];
            s += v.x * v.x + v.y * v.y + v.z * v.z + v.w * v.w;
        }
    }
    for (int off = 32; off; off >>= 1) s += __shfl_down(s, off, 64);
    if (lane == 0) kn[m] = (m < M_) ? s : FLT_MAX;
}

// ---------------- kernel 3: keys -> fp16, MFMA B-fragment order ----------------
// ksw[nb][kb][lane][j]: lane L holds B[k][n=nb*16+(L&15)] = keys[n][kb*32+(L>>4)*8+j]
__global__ __launch_bounds__(256) void k_ksw(const float* __restrict__ keys,
                                             _Float16* __restrict__ ksw) {
    int f = blockIdx.x * 256 + threadIdx.x;      // 131072 fragments
    int nb = f >> 10, rest = f & 1023;
    int kb = rest >> 6, L = rest & 63;
    int m = nb * 16 + (L & 15);
    int c = kb * 32 + ((L >> 4) * 8);
    half8 hv;
    if (m < M_) {
        float4 v0 = *(const float4*)(keys + (size_t)m * D_ + c);
        float4 v1 = *(const float4*)(keys + (size_t)m * D_ + c + 4);
        hv[0] = (_Float16)v0.x; hv[1] = (_Float16)v0.y;
        hv[2] = (_Float16)v0.z; hv[3] = (_Float16)v0.w;
        hv[4] = (_Float16)v1.x; hv[5] = (_Float16)v1.y;
        hv[6] = (_Float16)v1.z; hv[7] = (_Float16)v1.w;
    } else {
#pragma unroll
        for (int j = 0; j < 8; ++j) hv[j] = (_Float16)0.f;
    }
    *(half8*)(ksw + (size_t)f * 8) = hv;
}

// merge top-2 list (t1,j1,t2,j2) into (s1,i1,s2,i2); both sorted; idx tie-break.
__device__ inline void merge2(float& s1, unsigned& i1, float& s2, unsigned& i2,
                              float t1, unsigned j1, float t2, unsigned j2) {
    if (t1 < s1 || (t1 == s1 && j1 < i1)) {
        float os = s1; unsigned oi = i1;
        s1 = t1; i1 = j1;
        if (os < t2 || (os == t2 && oi < j2)) { s2 = os; i2 = oi; }
        else { s2 = t2; i2 = j2; }
    } else {
        if (t1 < s2 || (t1 == s2 && j1 < i2)) { s2 = t1; i2 = j1; }
    }
}

// ---------------- kernel 4: barrier-free MFMA score GEMM (R7 structure, y=4) ----------------
// qsw/ksw are fragment-ordered: each lane's 16B frag is one dwordx4 load — no LDS
// staging, no K-loop barriers. Depth-1 cur/nxt register prefetch (R7 code; R8's
// unrolled ping-pong blew VGPR 120->232 and halved occupancy — reverted).
// grid (N/128, 4) = 1024 blocks -> 4 blocks/CU (VGPR ~120 -> 4 waves/SIMD fits 480<512).
// Block: 128 px x 512 keys = 4 chunks of 128; g = ch*16 + dc (64 steps).
// Score s = kn - 2*acc > 0 -> float bits compare as unsigned; pack 4-bit local key id
// (ch*4+ni) into low mantissa: running top-2 = 3 int min/max per score (trunc 16 ulp
// ~1e-3, absorbed by k_heat's exact fp32 rescue). acc reset only AFTER full fold (R6 bug).
__global__ __launch_bounds__(256) void k_mfma(const _Float16* __restrict__ qsw,
                                              const _Float16* __restrict__ ksw,
                                              const float* __restrict__ kn,
                                              float4* __restrict__ best) {
    __shared__ float  kns[512];
    __shared__ float4 red[256];
    int t = threadIdx.x;
    int lane = t & 63;
    int w = __builtin_amdgcn_readfirstlane(t >> 6);
    int wr = w >> 1, wc = w & 1;
    int colk = lane & 15, quad = lane >> 4;
    int p0 = blockIdx.x * 128;
    int yb = blockIdx.y;                         // key quarter: yb*512
    int pb0 = p0 >> 4;

    // stage this block's kn range into LDS (keeps the K-loop free of scalar VMEM waits)
#pragma unroll
    for (int i = 0; i < 2; ++i) kns[t + 256 * i] = kn[yb * 512 + t + 256 * i];
    __syncthreads();

    // fragment base pointers (lane-resolved). A(pi,dc) = aq + pi*8192 + dc*512
    // B(ni,ch,dc) = bk + ch*65536 + ni*8192 + dc*512     (units: _Float16)
    const _Float16* aq = qsw + (size_t)(pb0 + wr * 4) * (16 * 512) + lane * 8;
    const _Float16* bk = ksw + (size_t)(yb * 32 + wc * 4) * (16 * 512) + lane * 8;

    unsigned pk1[16], pk2[16];
#pragma unroll
    for (int i = 0; i < 16; ++i) { pk1[i] = 0xFFFFFFFFu; pk2[i] = 0xFFFFFFFFu; }

    f32x4 acc[4][4];
#pragma unroll
    for (int pi = 0; pi < 4; ++pi)
#pragma unroll
        for (int ni = 0; ni < 4; ++ni) acc[pi][ni] = (f32x4){0.f, 0.f, 0.f, 0.f};

    half8 cur[8], nxt[8];
#pragma unroll
    for (int pi = 0; pi < 4; ++pi) cur[pi] = *(const half8*)(aq + pi * 8192);
#pragma unroll
    for (int ni = 0; ni < 4; ++ni) cur[4 + ni] = *(const half8*)(bk + ni * 8192);

#pragma unroll 2
    for (int g = 0; g < 64; ++g) {
        // prefetch step g+1 while computing step g
        if (g < 63) {
            int g1 = g + 1;
            int dc = g1 & 15, ch = g1 >> 4;
#pragma unroll
            for (int pi = 0; pi < 4; ++pi)
                nxt[pi] = *(const half8*)(aq + pi * 8192 + dc * 512);
#pragma unroll
            for (int ni = 0; ni < 4; ++ni)
                nxt[4 + ni] = *(const half8*)(bk + ch * 65536 + ni * 8192 + dc * 512);
        }
#pragma unroll
        for (int pi = 0; pi < 4; ++pi)
#pragma unroll
            for (int ni = 0; ni < 4; ++ni)
                acc[pi][ni] = __builtin_amdgcn_mfma_f32_16x16x32_f16(
                    cur[pi], cur[4 + ni], acc[pi][ni], 0, 0, 0);

        if ((g & 15) == 15) {                    // chunk complete: fold ALL scores...
            int ch = g >> 4;
            float kc[4];
#pragma unroll
            for (int ni = 0; ni < 4; ++ni) kc[ni] = kns[ch * 128 + wc * 64 + ni * 16 + colk];
#pragma unroll
            for (int pi = 0; pi < 4; ++pi) {
#pragma unroll
                for (int r = 0; r < 4; ++r) {
                    int si = pi * 4 + r;
#pragma unroll
                    for (int ni = 0; ni < 4; ++ni) {
                        float sc = fmaf(-2.0f, acc[pi][ni][r], kc[ni]);
                        unsigned p = (__float_as_uint(sc) & ~15u) | (unsigned)(ch * 4 + ni);
                        unsigned hi = pk1[si] > p ? pk1[si] : p;   // max
                        pk1[si] = pk1[si] < p ? pk1[si] : p;       // min
                        pk2[si] = pk2[si] < hi ? pk2[si] : hi;     // min
                    }
                }
            }
            // ...then reset accumulators (AFTER the fold — R6 bug was resetting inside)
#pragma unroll
            for (int pi = 0; pi < 4; ++pi)
#pragma unroll
                for (int ni = 0; ni < 4; ++ni)
                    acc[pi][ni] = (f32x4){0.f, 0.f, 0.f, 0.f};
        }
#pragma unroll
        for (int i = 0; i < 8; ++i) cur[i] = nxt[i];
    }

    // ---- once-per-block epilogue: unpack, butterfly over 16 colk lanes, LDS wc-merge ----
    __syncthreads();
#pragma unroll
    for (int pi = 0; pi < 4; ++pi) {
#pragma unroll
        for (int r = 0; r < 4; ++r) {
            int si = pi * 4 + r;
            int pix = wr * 64 + pi * 16 + quad * 4 + r;   // C/D: row = quad*4 + reg
            unsigned P1 = pk1[si], P2 = pk2[si];
            float s1 = __uint_as_float(P1 & ~15u);
            float s2 = __uint_as_float(P2 & ~15u);
            unsigned l1 = P1 & 15u, l2 = P2 & 15u;
            unsigned i1 = (unsigned)(yb * 512) + (l1 >> 2) * 128 + wc * 64 + (l1 & 3) * 16 + colk;
            unsigned i2 = (unsigned)(yb * 512) + (l2 >> 2) * 128 + wc * 64 + (l2 & 3) * 16 + colk;
#pragma unroll
            for (int mask = 1; mask < 16; mask <<= 1) {
                float t1 = __shfl_xor(s1, mask, 64);
                float t2 = __shfl_xor(s2, mask, 64);
                unsigned j1 = (unsigned)__shfl_xor((int)i1, mask, 64);
                unsigned j2 = (unsigned)__shfl_xor((int)i2, mask, 64);
                merge2(s1, i1, s2, i2, t1, j1, t2, j2);
            }
            if (colk == 0)
                red[pix * 2 + wc] = make_float4(s1, __uint_as_float(i1),
                                                s2, __uint_as_float(i2));
        }
    }
    __syncthreads();
    if (t < 128) {
        float4 e0 = red[t * 2 + 0];
        float4 e1 = red[t * 2 + 1];
        float s1 = e0.x, s2 = e0.z;
        unsigned i1 = __float_as_uint(e0.y), i2 = __float_as_uint(e0.w);
        merge2(s1, i1, s2, i2, e1.x, __float_as_uint(e1.y), e1.z, __float_as_uint(e1.w));
        best[(size_t)yb * N_ + p0 + t] =
            make_float4(s1, __uint_as_float(i1), s2, __uint_as_float(i2));
    }
}

// ---------------- kernel 5: merge 4 quarters -> top-2, exact fp32 rescue + heatmap ----------------
// Block = 64 pixels x 4 c-groups (256 thr); 512 blocks.
__global__ __launch_bounds__(256) void k_heat(
    const float* __restrict__ q, const float* __restrict__ keys,
    const float* __restrict__ kn, const float* __restrict__ rnorm,
    const float4* __restrict__ best, float* __restrict__ out)
{
    __shared__ float4 part[64][5];               // (dot0,dot1,hh0,hh1) x 4 cg, +1 pad
    int t = threadIdx.x;
    int pl = t & 63, cg = t >> 6;
    int p0 = blockIdx.x * 64;
    int p = p0 + pl;
    const float* qb = q + (size_t)(p / HW_) * (D_ * HW_) + (p % HW_);

    // merge the 4 per-quarter top-2 lists (redundantly in each cg thread)
    float4 e0 = best[p];
    float s1 = e0.x, s2 = e0.z;
    unsigned i1 = __float_as_uint(e0.y), i2 = __float_as_uint(e0.w);
#pragma unroll
    for (int yb = 1; yb < 4; ++yb) {
        float4 e = best[(size_t)yb * N_ + p];
        merge2(s1, i1, s2, i2, e.x, __float_as_uint(e.y), e.z, __float_as_uint(e.w));
    }

    float rn = rnorm[p];
    const float* kp0 = keys + (size_t)i1 * D_;
    const float* kp1 = keys + (size_t)i2 * D_;
    float dot0 = 0.f, dot1 = 0.f, hh0 = 0.f, hh1 = 0.f;
    for (int c = cg * 128; c < cg * 128 + 128; c += 4) {
        float qv[4];
#pragma unroll
        for (int j = 0; j < 4; ++j) qv[j] = qb[(size_t)(c + j) * HW_] * rn;  // coalesced
        float4 kv0 = *(const float4*)(kp0 + c);
        float4 kv1 = *(const float4*)(kp1 + c);
        dot0 += qv[0] * kv0.x + qv[1] * kv0.y + qv[2] * kv0.z + qv[3] * kv0.w;
        dot1 += qv[0] * kv1.x + qv[1] * kv1.y + qv[2] * kv1.z + qv[3] * kv1.w;
        float a0 = qv[0] - kv0.x, a1 = qv[1] - kv0.y, a2 = qv[2] - kv0.z, a3 = qv[3] - kv0.w;
        float b0 = qv[0] - kv1.x, b1 = qv[1] - kv1.y, b2 = qv[2] - kv1.z, b3 = qv[3] - kv1.w;
        float A0 = a0 * a0, A1 = a1 * a1, A2 = a2 * a2, A3 = a3 * a3;
        float B0 = b0 * b0, B1 = b1 * b1, B2 = b2 * b2, B3 = b3 * b3;
        hh0 += A0 * A0 + A1 * A1 + A2 * A2 + A3 * A3;
        hh1 += B0 * B0 + B1 * B1 + B2 * B2 + B3 * B3;
    }
    part[pl][cg] = make_float4(dot0, dot1, hh0, hh1);
    __syncthreads();
    if (t < 64) {                                // cg==0 thread for pixel t holds i1,i2
        float4 a = part[t][0], b = part[t][1], c4 = part[t][2], d = part[t][3];
        float dA = a.x + b.x + c4.x + d.x;
        float dB = a.y + b.y + c4.y + d.y;
        float hA = a.z + b.z + c4.z + d.z;
        float hB = a.w + b.w + c4.w + d.w;
        float sA = kn[i1] - 2.0f * dA;
        float sB = kn[i2] - 2.0f * dB;
        // argmin semantics: smaller exact score wins; tie -> smaller index
        bool takeB = (sB < sA) || (sB == sA && i2 < i1);
        out[p0 + t] = takeB ? hB : hA;
    }
}

extern "C" void kernel_launch(void* const* d_in, const int* in_sizes, int n_in,
                              void* d_out, int out_size, void* d_ws, size_t ws_size,
                              hipStream_t stream) {
    const float* query = (const float*)d_in[0];   // (8,512,64,64) f32
    const float* keys  = (const float*)d_in[1];   // (2000,512) f32
    float* out = (float*)d_out;                   // 32768 f32

    // workspace layout (~38 MB):
    char* ws = (char*)d_ws;
    _Float16* qsw   = (_Float16*)ws;                                 // N*D fp16  = 33.5 MB
    _Float16* ksw   = (_Float16*)(ws + (size_t)N_ * D_ * 2);         // MP*D fp16 = 2 MB
    float*    rnorm = (float*)(ws + (size_t)N_ * D_ * 2 + (size_t)MP_ * D_ * 2);
    float*    kn    = rnorm + N_;
    float4*   best  = (float4*)(kn + MP_);                           // 4*N float4 = 2 MB

    k_kn  <<<MP_ / 4,             256, 0, stream>>>(keys, kn);
    k_ksw <<<MP_ * D_ / 8 / 256,  256, 0, stream>>>(keys, ksw);
    k_prep<<<N_ / 64,             256, 0, stream>>>(query, rnorm, qsw);
    k_mfma<<<dim3(N_ / 128, 4),   256, 0, stream>>>(qsw, ksw, kn, best);
    k_heat<<<N_ / 64,             256, 0, stream>>>(query, keys, kn, rnorm, best, out);
}

// Round 10
// 216.490 us; speedup vs baseline: 1.0735x; 1.0735x over previous
//
#include <hip/hip_runtime.h>
#include <float.h>
#include <math.h>

// Problem constants: query (8,512,64,64) f32, keys (2000,512) f32
constexpr int D_  = 512;
constexpr int HW_ = 4096;           // 64*64
constexpr int N_  = 32768;          // B*HW
constexpr int M_  = 2000;
constexpr int MP_ = 2048;           // padded key count

typedef _Float16 half8 __attribute__((ext_vector_type(8)));
typedef float    f32x4 __attribute__((ext_vector_type(4)));

// ---------------- kernel 1: fused per-pixel rnorm + fp16 A-fragment swizzle ----------------
// qsw holds NORMALIZED q-hat (score downstream: s = kn - 2*acc; rnorm applied ONCE, here).
// qsw[pb][kb][lane][j]: lane L holds A[m = pb*16 + (L&15)][k = kb*32 + (L>>4)*8 + j]
__global__ __launch_bounds__(256) void k_prep(const float* __restrict__ q,
                                              float* __restrict__ rnorm,
                                              _Float16* __restrict__ qsw) {
    __shared__ float  tile[64][65];
    __shared__ float4 part2[16][17];
    __shared__ float  rns[64];
    int t = threadIdx.x;
    int p0 = blockIdx.x * 64;                    // 64 | 4096 -> single batch per block
    const float* base = q + (size_t)(p0 / HW_) * (D_ * HW_) + (p0 % HW_);

    // pass 1: sum of squares, float4-vectorized along hw (4 pixels per thread-lane)
    int px4 = t & 15, cgi = t >> 4;              // 16 pixel-quads x 16 c-groups of 32
    {
        const float* bb = base + px4 * 4;
        float s0 = 0.f, s1 = 0.f, s2 = 0.f, s3 = 0.f;
        for (int c = cgi * 32; c < cgi * 32 + 32; ++c) {
            float4 v = *(const float4*)(bb + (size_t)c * HW_);
            s0 += v.x * v.x; s1 += v.y * v.y; s2 += v.z * v.z; s3 += v.w * v.w;
        }
        part2[px4][cgi] = make_float4(s0, s1, s2, s3);
    }
    __syncthreads();
    if (t < 64) {
        float ss = 0.f;
#pragma unroll
        for (int g = 0; g < 16; ++g)
            ss += ((const float*)&part2[t >> 2][g])[t & 3];
        float rv = 1.0f / fmaxf(sqrtf(ss), 1e-12f);   // matches F.normalize eps
        rns[t] = rv;
        rnorm[p0 + t] = rv;
    }

    // pass 2: re-read (L2-hot), normalize, emit fragment-ordered fp16
    int pb0 = blockIdx.x * 4;
    for (int ct = 0; ct < 8; ++ct) {
        __syncthreads();                         // tile free + rns ready
#pragma unroll
        for (int i = 0; i < 4; ++i) {
            int sl = t + 256 * i;                // 1024 float4 slots: 64 ch-rows x 16
            int row = sl >> 4, p4 = (sl & 15) * 4;
            float4 v = *(const float4*)(base + (size_t)(ct * 64 + row) * HW_ + p4);
            tile[row][p4 + 0] = v.x; tile[row][p4 + 1] = v.y;
            tile[row][p4 + 2] = v.z; tile[row][p4 + 3] = v.w;
        }
        __syncthreads();
#pragma unroll
        for (int i = 0; i < 2; ++i) {
            int f = t + 256 * i;                 // 512 fragments: 8 tiles x 64 lanes
            int ti = f >> 6, L = f & 63;
            int pbi = ti & 3, kbi = ti >> 2;
            int plx = pbi * 16 + (L & 15);
            int cl = kbi * 32 + ((L >> 4) * 8);
            float rv = rns[plx];
            half8 hv;
#pragma unroll
            for (int j = 0; j < 8; ++j) hv[j] = (_Float16)(tile[cl + j][plx] * rv);
            size_t off = (((size_t)(pb0 + pbi) * 16 + (ct * 2 + kbi)) * 64 + L) * 8;
            *(half8*)(qsw + off) = hv;
        }
    }
}

// ---------------- kernel 2: fused |k|^2 + fp16 B-fragment swizzle (single keys pass) ----------------
// Wave per key row m: lane l covers channels kb*32+qd*8..+7 (kb=l>>2, qd=l&3) — 32 B/lane
// fully coalesced (wave covers the whole 2 KB row). Writes kn[m] (FLT_MAX pad) and the
// 64 B-fragments: ksw[(m>>4)*1024 + kb*64 + qd*16 + (m&15)] = fp16(keys[m][kb*32+qd*8..+7]).
__global__ __launch_bounds__(256) void k_keys(const float* __restrict__ keys,
                                              float* __restrict__ kn,
                                              _Float16* __restrict__ ksw) {
    int wave = threadIdx.x >> 6;
    int lane = threadIdx.x & 63;
    int m = blockIdx.x * 4 + wave;               // grid 512 -> m in [0,2048)
    int kb = lane >> 2, qd = lane & 3;
    float4 v0 = make_float4(0.f, 0.f, 0.f, 0.f);
    float4 v1 = make_float4(0.f, 0.f, 0.f, 0.f);
    if (m < M_) {
        const float* row = keys + (size_t)m * D_ + kb * 32 + qd * 8;
        v0 = *(const float4*)(row);
        v1 = *(const float4*)(row + 4);
    }
    // |k|^2 wave-reduction (8 elems/lane x 64 lanes = 512)
    float s = v0.x * v0.x + v0.y * v0.y + v0.z * v0.z + v0.w * v0.w
            + v1.x * v1.x + v1.y * v1.y + v1.z * v1.z + v1.w * v1.w;
    for (int off = 32; off; off >>= 1) s += __shfl_down(s, off, 64);
    if (lane == 0) kn[m] = (m < M_) ? s : FLT_MAX;
    // fragment emit (zeros for pad keys)
    half8 hv;
    hv[0] = (_Float16)v0.x; hv[1] = (_Float16)v0.y;
    hv[2] = (_Float16)v0.z; hv[3] = (_Float16)v0.w;
    hv[4] = (_Float16)v1.x; hv[5] = (_Float16)v1.y;
    hv[6] = (_Float16)v1.z; hv[7] = (_Float16)v1.w;
    size_t f = ((size_t)(m >> 4) * 16 + kb) * 64 + qd * 16 + (m & 15);
    *(half8*)(ksw + f * 8) = hv;
}

// merge top-2 list (t1,j1,t2,j2) into (s1,i1,s2,i2); both sorted; idx tie-break.
__device__ inline void merge2(float& s1, unsigned& i1, float& s2, unsigned& i2,
                              float t1, unsigned j1, float t2, unsigned j2) {
    if (t1 < s1 || (t1 == s1 && j1 < i1)) {
        float os = s1; unsigned oi = i1;
        s1 = t1; i1 = j1;
        if (os < t2 || (os == t2 && oi < j2)) { s2 = os; i2 = oi; }
        else { s2 = t2; i2 = j2; }
    } else {
        if (t1 < s2 || (t1 == s2 && j1 < i2)) { s2 = t1; i2 = j1; }
    }
}

// ---------------- kernel 3: barrier-free MFMA score GEMM (R7-exact) ----------------
// qsw/ksw are fragment-ordered: each lane's 16B frag is one dwordx4 load — no LDS
// staging, no K-loop barriers. Depth-1 cur/nxt register prefetch. grid (N/128, 2);
// 4 waves 2x2; 128 px x 1024 keys = 8 chunks of 128; g = ch*16 + dc (128 steps).
// Known regime (R7/R8/R9 post-mortems): ~184 regs/wave incl AGPR -> 2 blocks/CU;
// bound by L1 vector-return BW (~64 KB/CU-iter). Score s = kn - 2*acc > 0 -> float
// bits compare as unsigned; 5-bit local key id packed into low mantissa (trunc 32 ulp
// ~2e-3, absorbed by k_heat's exact fp32 rescue). acc reset AFTER full fold (R6 bug).
__global__ __launch_bounds__(256) void k_mfma(const _Float16* __restrict__ qsw,
                                              const _Float16* __restrict__ ksw,
                                              const float* __restrict__ kn,
                                              float4* __restrict__ best) {
    __shared__ float  kns[1024];
    __shared__ float4 red[256];
    int t = threadIdx.x;
    int lane = t & 63;
    int w = __builtin_amdgcn_readfirstlane(t >> 6);
    int wr = w >> 1, wc = w & 1;
    int colk = lane & 15, quad = lane >> 4;
    int p0 = blockIdx.x * 128;
    int yb = blockIdx.y;                         // key half: yb*1024
    int pb0 = p0 >> 4;

    // stage this block's kn range into LDS (keeps the K-loop free of scalar VMEM waits)
#pragma unroll
    for (int i = 0; i < 4; ++i) kns[t + 256 * i] = kn[yb * 1024 + t + 256 * i];
    __syncthreads();

    // fragment base pointers (lane-resolved). A(pi,dc) = aq + pi*8192 + dc*512
    // B(ni,ch,dc) = bk + ch*65536 + ni*8192 + dc*512     (units: _Float16)
    const _Float16* aq = qsw + (size_t)(pb0 + wr * 4) * (16 * 512) + lane * 8;
    const _Float16* bk = ksw + (size_t)(yb * 64 + wc * 4) * (16 * 512) + lane * 8;

    unsigned pk1[16], pk2[16];
#pragma unroll
    for (int i = 0; i < 16; ++i) { pk1[i] = 0xFFFFFFFFu; pk2[i] = 0xFFFFFFFFu; }

    f32x4 acc[4][4];
#pragma unroll
    for (int pi = 0; pi < 4; ++pi)
#pragma unroll
        for (int ni = 0; ni < 4; ++ni) acc[pi][ni] = (f32x4){0.f, 0.f, 0.f, 0.f};

    half8 cur[8], nxt[8];
#pragma unroll
    for (int pi = 0; pi < 4; ++pi) cur[pi] = *(const half8*)(aq + pi * 8192);
#pragma unroll
    for (int ni = 0; ni < 4; ++ni) cur[4 + ni] = *(const half8*)(bk + ni * 8192);

#pragma unroll 2
    for (int g = 0; g < 128; ++g) {
        // prefetch step g+1 while computing step g
        if (g < 127) {
            int g1 = g + 1;
            int dc = g1 & 15, ch = g1 >> 4;
#pragma unroll
            for (int pi = 0; pi < 4; ++pi)
                nxt[pi] = *(const half8*)(aq + pi * 8192 + dc * 512);
#pragma unroll
            for (int ni = 0; ni < 4; ++ni)
                nxt[4 + ni] = *(const half8*)(bk + ch * 65536 + ni * 8192 + dc * 512);
        }
#pragma unroll
        for (int pi = 0; pi < 4; ++pi)
#pragma unroll
            for (int ni = 0; ni < 4; ++ni)
                acc[pi][ni] = __builtin_amdgcn_mfma_f32_16x16x32_f16(
                    cur[pi], cur[4 + ni], acc[pi][ni], 0, 0, 0);

        if ((g & 15) == 15) {                    // chunk complete: fold ALL scores...
            int ch = g >> 4;
            float kc[4];
#pragma unroll
            for (int ni = 0; ni < 4; ++ni) kc[ni] = kns[ch * 128 + wc * 64 + ni * 16 + colk];
#pragma unroll
            for (int pi = 0; pi < 4; ++pi) {
#pragma unroll
                for (int r = 0; r < 4; ++r) {
                    int si = pi * 4 + r;
#pragma unroll
                    for (int ni = 0; ni < 4; ++ni) {
                        float sc = fmaf(-2.0f, acc[pi][ni][r], kc[ni]);
                        unsigned p = (__float_as_uint(sc) & ~31u) | (unsigned)(ch * 4 + ni);
                        unsigned hi = pk1[si] > p ? pk1[si] : p;   // max
                        pk1[si] = pk1[si] < p ? pk1[si] : p;       // min
                        pk2[si] = pk2[si] < hi ? pk2[si] : hi;     // min
                    }
                }
            }
            // ...then reset accumulators (AFTER the fold — R6 bug was resetting inside)
#pragma unroll
            for (int pi = 0; pi < 4; ++pi)
#pragma unroll
                for (int ni = 0; ni < 4; ++ni)
                    acc[pi][ni] = (f32x4){0.f, 0.f, 0.f, 0.f};
        }
#pragma unroll
        for (int i = 0; i < 8; ++i) cur[i] = nxt[i];
    }

    // ---- once-per-block epilogue: unpack, butterfly over 16 colk lanes, LDS wc-merge ----
    __syncthreads();
#pragma unroll
    for (int pi = 0; pi < 4; ++pi) {
#pragma unroll
        for (int r = 0; r < 4; ++r) {
            int si = pi * 4 + r;
            int pix = wr * 64 + pi * 16 + quad * 4 + r;   // C/D: row = quad*4 + reg
            unsigned P1 = pk1[si], P2 = pk2[si];
            float s1 = __uint_as_float(P1 & ~31u);
            float s2 = __uint_as_float(P2 & ~31u);
            unsigned l1 = P1 & 31u, l2 = P2 & 31u;
            unsigned i1 = (unsigned)(yb * 1024) + (l1 >> 2) * 128 + wc * 64 + (l1 & 3) * 16 + colk;
            unsigned i2 = (unsigned)(yb * 1024) + (l2 >> 2) * 128 + wc * 64 + (l2 & 3) * 16 + colk;
#pragma unroll
            for (int mask = 1; mask < 16; mask <<= 1) {
                float t1 = __shfl_xor(s1, mask, 64);
                float t2 = __shfl_xor(s2, mask, 64);
                unsigned j1 = (unsigned)__shfl_xor((int)i1, mask, 64);
                unsigned j2 = (unsigned)__shfl_xor((int)i2, mask, 64);
                merge2(s1, i1, s2, i2, t1, j1, t2, j2);
            }
            if (colk == 0)
                red[pix * 2 + wc] = make_float4(s1, __uint_as_float(i1),
                                                s2, __uint_as_float(i2));
        }
    }
    __syncthreads();
    if (t < 128) {
        float4 e0 = red[t * 2 + 0];
        float4 e1 = red[t * 2 + 1];
        float s1 = e0.x, s2 = e0.z;
        unsigned i1 = __float_as_uint(e0.y), i2 = __float_as_uint(e0.w);
        merge2(s1, i1, s2, i2, e1.x, __float_as_uint(e1.y), e1.z, __float_as_uint(e1.w));
        best[(size_t)yb * N_ + p0 + t] =
            make_float4(s1, __uint_as_float(i1), s2, __uint_as_float(i2));
    }
}

// ---------------- kernel 4: merge 2 halves -> top-2, exact fp32 rescue + heatmap ----------------
// Block = 64 pixels x 4 c-groups (256 thr); 512 blocks. Reads fp32 q (NOT qsw): the
// rescue must be exact fp32 — fp16 q-hat here would inject ~1.4e-3 shared score error
// and ~7 expected argmin flips across the image (analyzed R10).
__global__ __launch_bounds__(256) void k_heat(
    const float* __restrict__ q, const float* __restrict__ keys,
    const float* __restrict__ kn, const float* __restrict__ rnorm,
    const float4* __restrict__ best, float* __restrict__ out)
{
    __shared__ float4 part[64][5];               // (dot0,dot1,hh0,hh1) x 4 cg, +1 pad
    int t = threadIdx.x;
    int pl = t & 63, cg = t >> 6;
    int p0 = blockIdx.x * 64;
    int p = p0 + pl;
    const float* qb = q + (size_t)(p / HW_) * (D_ * HW_) + (p % HW_);

    // merge the 2 per-half top-2 lists (redundantly in each cg thread)
    float4 e0 = best[p];
    float4 e1 = best[N_ + p];
    float s1 = e0.x, s2 = e0.z;
    unsigned i1 = __float_as_uint(e0.y), i2 = __float_as_uint(e0.w);
    merge2(s1, i1, s2, i2, e1.x, __float_as_uint(e1.y), e1.z, __float_as_uint(e1.w));

    float rn = rnorm[p];
    const float* kp0 = keys + (size_t)i1 * D_;
    const float* kp1 = keys + (size_t)i2 * D_;
    float dot0 = 0.f, dot1 = 0.f, hh0 = 0.f, hh1 = 0.f;
    for (int c = cg * 128; c < cg * 128 + 128; c += 4) {
        float qv[4];
#pragma unroll
        for (int j = 0; j < 4; ++j) qv[j] = qb[(size_t)(c + j) * HW_] * rn;  // coalesced
        float4 kv0 = *(const float4*)(kp0 + c);
        float4 kv1 = *(const float4*)(kp1 + c);
        dot0 += qv[0] * kv0.x + qv[1] * kv0.y + qv[2] * kv0.z + qv[3] * kv0.w;
        dot1 += qv[0] * kv1.x + qv[1] * kv1.y + qv[2] * kv1.z + qv[3] * kv1.w;
        float a0 = qv[0] - kv0.x, a1 = qv[1] - kv0.y, a2 = qv[2] - kv0.z, a3 = qv[3] - kv0.w;
        float b0 = qv[0] - kv1.x, b1 = qv[1] - kv1.y, b2 = qv[2] - kv1.z, b3 = qv[3] - kv1.w;
        float A0 = a0 * a0, A1 = a1 * a1, A2 = a2 * a2, A3 = a3 * a3;
        float B0 = b0 * b0, B1 = b1 * b1, B2 = b2 * b2, B3 = b3 * b3;
        hh0 += A0 * A0 + A1 * A1 + A2 * A2 + A3 * A3;
        hh1 += B0 * B0 + B1 * B1 + B2 * B2 + B3 * B3;
    }
    part[pl][cg] = make_float4(dot0, dot1, hh0, hh1);
    __syncthreads();
    if (t < 64) {                                // cg==0 thread for pixel t holds i1,i2
        float4 a = part[t][0], b = part[t][1], c4 = part[t][2], d = part[t][3];
        float dA = a.x + b.x + c4.x + d.x;
        float dB = a.y + b.y + c4.y + d.y;
        float hA = a.z + b.z + c4.z + d.z;
        float hB = a.w + b.w + c4.w + d.w;
        float sA = kn[i1] - 2.0f * dA;
        float sB = kn[i2] - 2.0f * dB;
        // argmin semantics: smaller exact score wins; tie -> smaller index
        bool takeB = (sB < sA) || (sB == sA && i2 < i1);
        out[p0 + t] = takeB ? hB : hA;
    }
}

extern "C" void kernel_launch(void* const* d_in, const int* in_sizes, int n_in,
                              void* d_out, int out_size, void* d_ws, size_t ws_size,
                              hipStream_t stream) {
    const float* query = (const float*)d_in[0];   // (8,512,64,64) f32
    const float* keys  = (const float*)d_in[1];   // (2000,512) f32
    float* out = (float*)d_out;                   // 32768 f32

    // workspace layout (~37 MB):
    char* ws = (char*)d_ws;
    _Float16* qsw   = (_Float16*)ws;                                 // N*D fp16  = 33.5 MB
    _Float16* ksw   = (_Float16*)(ws + (size_t)N_ * D_ * 2);         // MP*D fp16 = 2 MB
    float*    rnorm = (float*)(ws + (size_t)N_ * D_ * 2 + (size_t)MP_ * D_ * 2);
    float*    kn    = rnorm + N_;
    float4*   best  = (float4*)(kn + MP_);                           // 2*N float4 = 1 MB

    k_keys<<<MP_ / 4,           256, 0, stream>>>(keys, kn, ksw);
    k_prep<<<N_ / 64,           256, 0, stream>>>(query, rnorm, qsw);
    k_mfma<<<dim3(N_ / 128, 2), 256, 0, stream>>>(qsw, ksw, kn, best);
    k_heat<<<N_ / 64,           256, 0, stream>>>(query, keys, kn, rnorm, best, out);
}

// Round 11
// 181.442 us; speedup vs baseline: 1.2809x; 1.1932x over previous
//
#include <hip/hip_runtime.h>
#include <float.h>
#include <math.h>

// Problem constants: query (8,512,64,64) f32, keys (2000,512) f32
constexpr int D_  = 512;
constexpr int HW_ = 4096;           // 64*64
constexpr int N_  = 32768;          // B*HW
constexpr int M_  = 2000;
constexpr int MP_ = 2048;           // padded key count

constexpr float QS = 16.0f;         // q-hat pre-scale before fp8 (keeps e4m3 in normal range)

typedef int          i32x8  __attribute__((ext_vector_type(8)));
typedef float        f32x16 __attribute__((ext_vector_type(16)));
typedef unsigned int uu32x4 __attribute__((ext_vector_type(4)));
typedef unsigned int uu32x2 __attribute__((ext_vector_type(2)));

__device__ inline unsigned umn(unsigned a, unsigned b) { return a < b ? a : b; }
__device__ inline unsigned umx(unsigned a, unsigned b) { return a > b ? a : b; }

// pack 4 floats -> 4 OCP e4m3 bytes (v_cvt_pk_fp8_f32; OCP format on gfx950)
__device__ inline unsigned pk4f8(float a, float b, float c, float d) {
    int v = 0;
    v = __builtin_amdgcn_cvt_pk_fp8_f32(a, b, v, false);   // bytes 0-1
    v = __builtin_amdgcn_cvt_pk_fp8_f32(c, d, v, true);    // bytes 2-3
    return (unsigned)v;
}

// ---------------- kernel 1: per-pixel rnorm + fp8 A-fragment swizzle ----------------
// qsw8 holds q-hat * QS in e4m3, 32x32x64-A-fragment order:
// frag (pb32, kc64): lane L byte j  <->  A[m = pb*32 + (L&31)][k = kc*64 + (L>>5)*32 + j]
__global__ __launch_bounds__(256) void k_prep(const float* __restrict__ q,
                                              float* __restrict__ rnorm,
                                              unsigned char* __restrict__ qsw8) {
    __shared__ float  tile[64][65];
    __shared__ float4 part2[16][17];
    __shared__ float  rns[64];
    int t = threadIdx.x;
    int p0 = blockIdx.x * 64;                    // 64 | 4096 -> single batch per block
    const float* base = q + (size_t)(p0 / HW_) * (D_ * HW_) + (p0 % HW_);

    // pass 1: sum of squares, float4-vectorized along hw
    int px4 = t & 15, cgi = t >> 4;
    {
        const float* bb = base + px4 * 4;
        float s0 = 0.f, s1 = 0.f, s2 = 0.f, s3 = 0.f;
        for (int c = cgi * 32; c < cgi * 32 + 32; ++c) {
            float4 v = *(const float4*)(bb + (size_t)c * HW_);
            s0 += v.x * v.x; s1 += v.y * v.y; s2 += v.z * v.z; s3 += v.w * v.w;
        }
        part2[px4][cgi] = make_float4(s0, s1, s2, s3);
    }
    __syncthreads();
    if (t < 64) {
        float ss = 0.f;
#pragma unroll
        for (int g = 0; g < 16; ++g)
            ss += ((const float*)&part2[t >> 2][g])[t & 3];
        float rv = 1.0f / fmaxf(sqrtf(ss), 1e-12f);   // matches F.normalize eps
        rns[t] = rv;
        rnorm[p0 + t] = rv;
    }

    // pass 2: re-read (L2-hot), normalize+scale, emit fp8 fragments
    int pb0 = blockIdx.x * 2;                    // pb32 base (2 per block)
    for (int ct = 0; ct < 8; ++ct) {             // kc64 = ct
        __syncthreads();
#pragma unroll
        for (int i = 0; i < 4; ++i) {
            int sl = t + 256 * i;                // 1024 float4 slots: 64 ch-rows x 16
            int row = sl >> 4, p4 = (sl & 15) * 4;
            float4 v = *(const float4*)(base + (size_t)(ct * 64 + row) * HW_ + p4);
            tile[row][p4 + 0] = v.x; tile[row][p4 + 1] = v.y;
            tile[row][p4 + 2] = v.z; tile[row][p4 + 3] = v.w;
        }
        __syncthreads();
        {
            // 256 slots: 2 pb-frags x 64 lanes x 2 16B-halves
            int pbi = t >> 7, L = (t >> 1) & 63, hf = t & 1;
            int plx = pbi * 32 + (L & 31);
            int cl  = (L >> 5) * 32 + hf * 16;
            float rv = rns[plx] * QS;
            unsigned d[4];
#pragma unroll
            for (int w4 = 0; w4 < 4; ++w4)
                d[w4] = pk4f8(tile[cl + w4 * 4 + 0][plx] * rv,
                              tile[cl + w4 * 4 + 1][plx] * rv,
                              tile[cl + w4 * 4 + 2][plx] * rv,
                              tile[cl + w4 * 4 + 3][plx] * rv);
            *(uu32x4*)(qsw8 + (((size_t)(pb0 + pbi) * 8 + ct) * 64 + L) * 32 + hf * 16)
                = (uu32x4){d[0], d[1], d[2], d[3]};
        }
    }
}

// ---------------- kernel 2: fused |k|^2 + fp8 B-fragment swizzle ----------------
// frag (nb32, kc64): lane L byte j <-> B[k = kc*64 + (L>>5)*32 + j][n = nb*32 + (L&31)]
//                                   = keys[nb*32 + (L&31)][...]
__global__ __launch_bounds__(256) void k_keys(const float* __restrict__ keys,
                                              float* __restrict__ kn,
                                              unsigned char* __restrict__ ksw8) {
    int wave = threadIdx.x >> 6;
    int lane = threadIdx.x & 63;
    int m = blockIdx.x * 4 + wave;               // grid 512 -> m in [0,2048)
    int kc = lane >> 3, sub = lane & 7;
    int kh = sub >> 2, bg = sub & 3;
    int c = kc * 64 + kh * 32 + bg * 8;          // 8 channels per lane, covers all 512
    float4 v0 = make_float4(0.f, 0.f, 0.f, 0.f);
    float4 v1 = make_float4(0.f, 0.f, 0.f, 0.f);
    if (m < M_) {
        const float* row = keys + (size_t)m * D_ + c;
        v0 = *(const float4*)(row);
        v1 = *(const float4*)(row + 4);
    }
    float s = v0.x * v0.x + v0.y * v0.y + v0.z * v0.z + v0.w * v0.w
            + v1.x * v1.x + v1.y * v1.y + v1.z * v1.z + v1.w * v1.w;
    for (int off = 32; off; off >>= 1) s += __shfl_down(s, off, 64);
    if (lane == 0) kn[m] = (m < M_) ? s : FLT_MAX;
    unsigned d0 = pk4f8(v0.x, v0.y, v0.z, v0.w);
    unsigned d1 = pk4f8(v1.x, v1.y, v1.z, v1.w);
    *(uu32x2*)(ksw8 + (((size_t)(m >> 5) * 8 + kc) * 64 + kh * 32 + (m & 31)) * 32 + bg * 8)
        = (uu32x2){d0, d1};
}

// insert (t,j) into sorted top-3 (s1<=s2<=s3) with index tie-break
__device__ inline void insert3(float& s1, unsigned& i1, float& s2, unsigned& i2,
                               float& s3, unsigned& i3, float t, unsigned j) {
    if (t < s1 || (t == s1 && j < i1))      { s3 = s2; i3 = i2; s2 = s1; i2 = i1; s1 = t; i1 = j; }
    else if (t < s2 || (t == s2 && j < i2)) { s3 = s2; i3 = i2; s2 = t; i2 = j; }
    else if (t < s3 || (t == s3 && j < i3)) { s3 = t; i3 = j; }
}

// ---------------- kernel 3: fp8 MX MFMA score GEMM (32x32x64, scales = 1.0) ----------------
// Barrier-free K-loop, depth-1 cur/nxt prefetch (R7 structure). Wave = 32 px x 128 keys
// (1x4 frags); 4 waves stack 128 px -> every pixel is wave-private (no cross-wave merge).
// grid (N/128, 2); per block: 8 chunks of 128 keys; g = ch*8 + kc (64 steps of K=64).
// Score s = kn - (2/QS)*acc > 0 -> float bits compare as unsigned. 10-bit id
// ((ch*4+ni)<<5 | colk) packed into low mantissa (~0.06 trunc; fp8 noise ~0.05 — both
// absorbed by the top-3 + exact-fp32 rescue). Running top-3 = 5 int min/max per score.
__global__ __launch_bounds__(256) void k_mfma(const unsigned char* __restrict__ qsw8,
                                              const unsigned char* __restrict__ ksw8,
                                              const float* __restrict__ kn,
                                              float4* __restrict__ best12,
                                              float2* __restrict__ best3) {
    __shared__ float kns[1024];
    int t = threadIdx.x;
    int lane = t & 63;
    int wr = __builtin_amdgcn_readfirstlane(t >> 6);   // pixel-row group 0..3
    int colk = lane & 31, h = lane >> 5;
    int p0 = blockIdx.x * 128;
    int yb = blockIdx.y;                               // key half: yb*1024
#pragma unroll
    for (int i = 0; i < 4; ++i) kns[t + 256 * i] = kn[yb * 1024 + t + 256 * i];
    __syncthreads();

    // lane-resolved fragment bases (bytes). A(kc) = aq + kc*2048;
    // B(ni,ch,kc) = bk + ((ch*4+ni)*8 + kc)*2048
    const unsigned char* aq = qsw8 + ((size_t)(blockIdx.x * 4 + wr) * 8) * 2048 + lane * 32;
    const unsigned char* bk = ksw8 + ((size_t)(yb * 32) * 8) * 2048 + lane * 32;

    unsigned pk1[16], pk2[16], pk3[16];
#pragma unroll
    for (int i = 0; i < 16; ++i) { pk1[i] = 0xFFFFFFFFu; pk2[i] = 0xFFFFFFFFu; pk3[i] = 0xFFFFFFFFu; }

    f32x16 acc[4];
#pragma unroll
    for (int ni = 0; ni < 4; ++ni)
#pragma unroll
        for (int r = 0; r < 16; ++r) acc[ni][r] = 0.f;

    int scl = 0x7F7F7F7F;                        // e8m0 = 127 -> x1.0 in every byte/lane

    i32x8 curA, nxtA, curB[4], nxtB[4];
    curA = *(const i32x8*)(aq);
#pragma unroll
    for (int ni = 0; ni < 4; ++ni) curB[ni] = *(const i32x8*)(bk + (size_t)(ni * 8) * 2048);

#pragma unroll 2
    for (int g = 0; g < 64; ++g) {
        if (g < 63) {                            // prefetch step g+1
            int g1 = g + 1;
            int kc = g1 & 7, ch = g1 >> 3;
            nxtA = *(const i32x8*)(aq + (size_t)kc * 2048);
#pragma unroll
            for (int ni = 0; ni < 4; ++ni)
                nxtB[ni] = *(const i32x8*)(bk + (size_t)((ch * 4 + ni) * 8 + kc) * 2048);
        }
#pragma unroll
        for (int ni = 0; ni < 4; ++ni)
            acc[ni] = __builtin_amdgcn_mfma_scale_f32_32x32x64_f8f6f4(
                curA, curB[ni], acc[ni], 0, 0, 0, scl, 0, scl);

        if ((g & 7) == 7) {                      // chunk complete: fold ALL scores...
            int ch = g >> 3;
            float kc4[4];
#pragma unroll
            for (int ni = 0; ni < 4; ++ni) kc4[ni] = kns[ch * 128 + ni * 32 + colk];
#pragma unroll
            for (int ni = 0; ni < 4; ++ni) {
                unsigned idbase = ((unsigned)(ch * 4 + ni) << 5) | (unsigned)colk;
#pragma unroll
                for (int r = 0; r < 16; ++r) {
                    float sc = fmaf(-2.0f / QS, acc[ni][r], kc4[ni]);
                    unsigned p = (__float_as_uint(sc) & ~1023u) | idbase;
                    unsigned hi1 = umx(pk1[r], p);  pk1[r] = umn(pk1[r], p);
                    unsigned hi2 = umx(pk2[r], hi1); pk2[r] = umn(pk2[r], hi1);
                    pk3[r] = umn(pk3[r], hi2);
                }
            }
            // ...then reset accumulators (AFTER the full fold — R6 lesson)
#pragma unroll
            for (int ni = 0; ni < 4; ++ni)
#pragma unroll
                for (int r = 0; r < 16; ++r) acc[ni][r] = 0.f;
        }
#pragma unroll
        for (int ni = 0; ni < 4; ++ni) curB[ni] = nxtB[ni];
        curA = nxtA;
    }

    // ---- epilogue: packed-list butterfly over the 32 colk lanes; writers store top-3 ----
#pragma unroll
    for (int r = 0; r < 16; ++r) {
        unsigned a1 = pk1[r], a2 = pk2[r], a3 = pk3[r];
#pragma unroll
        for (int mask = 1; mask < 32; mask <<= 1) {
            unsigned b1 = (unsigned)__shfl_xor((int)a1, mask, 64);
            unsigned b2 = (unsigned)__shfl_xor((int)a2, mask, 64);
            unsigned b3 = (unsigned)__shfl_xor((int)a3, mask, 64);
            unsigned x1 = umn(a1, b1), y1 = umx(a1, b1);
            unsigned x2 = umn(a2, b2);
            unsigned z  = umn(a3, b3);
            a1 = x1;
            a2 = umn(y1, x2);
            a3 = umn(umx(y1, x2), z);
        }
        if (colk == 0) {
            int pix = wr * 32 + (r & 3) + 8 * (r >> 2) + 4 * h;   // 32x32 C/D row map
            // unpack: score (trunc) + global key index
            unsigned l1 = a1 & 1023u, l2 = a2 & 1023u, l3 = a3 & 1023u;
            unsigned m1 = (unsigned)(yb * 1024) + (l1 >> 7) * 128 + ((l1 >> 5) & 3) * 32 + (l1 & 31);
            unsigned m2 = (unsigned)(yb * 1024) + (l2 >> 7) * 128 + ((l2 >> 5) & 3) * 32 + (l2 & 31);
            unsigned m3 = (unsigned)(yb * 1024) + (l3 >> 7) * 128 + ((l3 >> 5) & 3) * 32 + (l3 & 31);
            size_t o = (size_t)yb * N_ + p0 + pix;
            best12[o] = make_float4(__uint_as_float(a1 & ~1023u), __uint_as_float(m1),
                                    __uint_as_float(a2 & ~1023u), __uint_as_float(m2));
            best3[o]  = make_float2(__uint_as_float(a3 & ~1023u), __uint_as_float(m3));
        }
    }
}

// ---------------- kernel 4: merge 6 cands -> approx-top-3, exact fp32 rescue + heatmap ----------------
// Block = 64 pixels x 4 c-groups (256 thr). Reads fp32 q (NOT fp8): rescue must be exact.
__global__ __launch_bounds__(256) void k_heat(
    const float* __restrict__ q, const float* __restrict__ keys,
    const float* __restrict__ kn, const float* __restrict__ rnorm,
    const float4* __restrict__ best12, const float2* __restrict__ best3,
    float* __restrict__ out)
{
    __shared__ float4 pA[64][5];                 // (d0,d1,d2,h0) x 4 cg (+1 pad)
    __shared__ float4 pB[64][5];                 // (h1,h2,-,-)
    int t = threadIdx.x;
    int pl = t & 63, cg = t >> 6;
    int p0 = blockIdx.x * 64;
    int p = p0 + pl;
    const float* qb = q + (size_t)(p / HW_) * (D_ * HW_) + (p % HW_);

    // gather the 2 halves' top-3 lists, merge to approx-top-3 (redundant per cg)
    float4 eA = best12[p];          float2 eA3 = best3[p];
    float4 eB = best12[N_ + p];     float2 eB3 = best3[N_ + p];
    float s1 = eA.x, s2 = eA.z, s3 = eA3.x;
    unsigned i1 = __float_as_uint(eA.y), i2 = __float_as_uint(eA.w), i3 = __float_as_uint(eA3.y);
    insert3(s1, i1, s2, i2, s3, i3, eB.x,  __float_as_uint(eB.y));
    insert3(s1, i1, s2, i2, s3, i3, eB.z,  __float_as_uint(eB.w));
    insert3(s1, i1, s2, i2, s3, i3, eB3.x, __float_as_uint(eB3.y));
    unsigned ci[3] = { i1, i2, i3 };

    float rn = rnorm[p];
    const float* kp0 = keys + (size_t)ci[0] * D_;
    const float* kp1 = keys + (size_t)ci[1] * D_;
    const float* kp2 = keys + (size_t)ci[2] * D_;
    float d0 = 0.f, d1 = 0.f, d2 = 0.f, h0 = 0.f, h1 = 0.f, h2 = 0.f;
    for (int c = cg * 128; c < cg * 128 + 128; c += 4) {
        float qv[4];
#pragma unroll
        for (int j = 0; j < 4; ++j) qv[j] = qb[(size_t)(c + j) * HW_] * rn;  // coalesced
        float4 k0 = *(const float4*)(kp0 + c);
        float4 k1 = *(const float4*)(kp1 + c);
        float4 k2 = *(const float4*)(kp2 + c);
        d0 += qv[0] * k0.x + qv[1] * k0.y + qv[2] * k0.z + qv[3] * k0.w;
        d1 += qv[0] * k1.x + qv[1] * k1.y + qv[2] * k1.z + qv[3] * k1.w;
        d2 += qv[0] * k2.x + qv[1] * k2.y + qv[2] * k2.z + qv[3] * k2.w;
#pragma unroll
        for (int j = 0; j < 4; ++j) {
            float kj0 = ((const float*)&k0)[j], kj1 = ((const float*)&k1)[j], kj2 = ((const float*)&k2)[j];
            float a = qv[j] - kj0, b = qv[j] - kj1, cc = qv[j] - kj2;
            float a2 = a * a, b2 = b * b, c2 = cc * cc;
            h0 += a2 * a2; h1 += b2 * b2; h2 += c2 * c2;
        }
    }
    pA[pl][cg] = make_float4(d0, d1, d2, h0);
    pB[pl][cg] = make_float4(h1, h2, 0.f, 0.f);
    __syncthreads();
    if (t < 64) {                                // cg==0 thread for pixel t holds ci[]
        float D0 = 0.f, D1 = 0.f, D2 = 0.f, H0 = 0.f, H1 = 0.f, H2 = 0.f;
#pragma unroll
        for (int g = 0; g < 4; ++g) {
            float4 a = pA[t][g], b = pB[t][g];
            D0 += a.x; D1 += a.y; D2 += a.z; H0 += a.w; H1 += b.x; H2 += b.y;
        }
        float sA = kn[ci[0]] - 2.0f * D0;
        float sB = kn[ci[1]] - 2.0f * D1;
        float sC = kn[ci[2]] - 2.0f * D2;
        // exact argmin among candidates; tie -> smaller index
        float bs = sA; unsigned bi = ci[0]; float bh = H0;
        if (sB < bs || (sB == bs && ci[1] < bi)) { bs = sB; bi = ci[1]; bh = H1; }
        if (sC < bs || (sC == bs && ci[2] < bi)) { bs = sC; bi = ci[2]; bh = H2; }
        out[p0 + t] = bh;
    }
}

extern "C" void kernel_launch(void* const* d_in, const int* in_sizes, int n_in,
                              void* d_out, int out_size, void* d_ws, size_t ws_size,
                              hipStream_t stream) {
    const float* query = (const float*)d_in[0];   // (8,512,64,64) f32
    const float* keys  = (const float*)d_in[1];   // (2000,512) f32
    float* out = (float*)d_out;                   // 32768 f32

    // workspace layout (~20 MB):
    char* ws = (char*)d_ws;
    unsigned char* qsw8 = (unsigned char*)ws;                        // N*D fp8   = 16.8 MB
    unsigned char* ksw8 = qsw8 + (size_t)N_ * D_;                    // MP*D fp8  = 1 MB
    float*  rnorm  = (float*)(ksw8 + (size_t)MP_ * D_);
    float*  kn     = rnorm + N_;
    float4* best12 = (float4*)(kn + MP_);                            // 2*N float4 = 1 MB
    float2* best3  = (float2*)(best12 + 2 * (size_t)N_);             // 2*N float2 = 0.5 MB

    k_keys<<<MP_ / 4,           256, 0, stream>>>(keys, kn, ksw8);
    k_prep<<<N_ / 64,           256, 0, stream>>>(query, rnorm, qsw8);
    k_mfma<<<dim3(N_ / 128, 2), 256, 0, stream>>>(qsw8, ksw8, kn, best12, best3);
    k_heat<<<N_ / 64,           256, 0, stream>>>(query, keys, kn, rnorm, best12, best3, out);
}